// Round 5
// baseline (552.027 us; speedup 1.0000x reference)
//
#include <hip/hip_runtime.h>

#define M_DIM 65536
#define K_DIM 2048
#define N_DIM 1024
#define EPSV 1e-5f

typedef __bf16 bf16;
typedef bf16 bf16x8 __attribute__((ext_vector_type(8)));
typedef bf16 bf16x4 __attribute__((ext_vector_type(4)));
typedef float f32x4 __attribute__((ext_vector_type(4)));

// monotone float <-> uint encoding for atomicMin on float
__device__ inline unsigned fenc(float f) {
    unsigned u = __float_as_uint(f);
    return (u & 0x80000000u) ? ~u : (u | 0x80000000u);
}
__device__ inline float fdec(unsigned e) {
    unsigned u = (e & 0x80000000u) ? (e & 0x7fffffffu) : ~e;
    return __uint_as_float(u);
}

__device__ __forceinline__ void gload_lds16(const bf16* g, bf16* l) {
    __builtin_amdgcn_global_load_lds(
        (const __attribute__((address_space(1))) unsigned int*)g,
        (__attribute__((address_space(3))) unsigned int*)l, 16, 0, 0);
}

// fp32 -> bf16 conversion (used for W only now; 4 MB, ~2 us)
__global__ void cvt_kernel(const float* __restrict__ in, bf16* __restrict__ out, long n4) {
    long i = (long)blockIdx.x * blockDim.x + threadIdx.x;
    long stride = (long)gridDim.x * blockDim.x;
    for (; i < n4; i += stride) {
        float4 v = ((const float4*)in)[i];
        bf16x4 h;
        h[0] = (bf16)v.x; h[1] = (bf16)v.y; h[2] = (bf16)v.z; h[3] = (bf16)v.w;
        ((bf16x4*)out)[i] = h;
    }
}

// B staging: one [256 rows][32 k] bf16 half-tile (16 KB), 512 threads x 2
// global_load_lds(16B). LDS dest LINEAR; XOR swizzle (granule ^= (row>>1)&3)
// applied to the GLOBAL source (both-sides involution). Conflict-free (R2: 0).
__device__ __forceinline__ void stage_half(const bf16* __restrict__ g0, int kbase,
                                           bf16* slot, int tid) {
#pragma unroll
    for (int i = 0; i < 2; ++i) {
        int gidx = i * 512 + tid;           // 16B granule id, 1024 per half-tile
        int row = gidx >> 2;                // 4 granules (64B) per row
        int gsw = (gidx & 3) ^ ((row >> 1) & 3);
        gload_lds16(g0 + (size_t)row * K_DIM + kbase + gsw * 8,
                    slot + (size_t)(i * 512 + (tid & 448)) * 8);  // wave-uniform base
    }
}

// LDS slot layout: A[parity][khalf], B[parity][khalf], each [256][32] bf16 = 16KB.
#define ASL(P, H) (lds + ((P) * 2 + (H)) * 8192)
#define BSL(P, H) (lds + 32768 + ((P) * 2 + (H)) * 8192)

// 256x256 tile, BK=64 split in two K-halves of 32; 8 waves (2Mx4N), per-wave
// 128x64 output (8x4 frags of 16x16x32). 8 phases per iter covering 2 K-tiles.
// A is staged FROM FP32 GLOBAL (T14 split): issue 4 coalesced dwordx4 at phase
// P, convert+swizzled-ds_write at P+2. The commit's register dependency forces
// a vmcnt wait that (oldest-first) also drains the B global_load_lds issued
// >=2 phases before their readers — no explicit vmcnt needed. B path and the
// fused GroupNorm+rowmin epilogue unchanged from R4.
__global__ __launch_bounds__(512, 2)
void gemm_fused(const float* __restrict__ X, const bf16* __restrict__ Wb,
                const float* __restrict__ gnw, const float* __restrict__ gnb,
                unsigned* __restrict__ rowmin) {
    extern __shared__ __align__(16) bf16 lds[];  // 128 KiB dynamic

    const int tid = threadIdx.x;
    const int wave = tid >> 6, lane = tid & 63;
    const int wr = wave >> 2, wc = wave & 3;     // 2 x 4 wave grid
    const int q = lane >> 4, r = lane & 15;

    // T1: bijective XCD-chunked block swizzle (1024 blocks % 8 == 0)
    const int bid = blockIdx.x;
    const int swz = (bid & 7) * 128 + (bid >> 3);
    const int bx = swz & 3, by = swz >> 2;
    const int brow = by * 256, bcol = bx * 256;

    const float* Arowf = X + (size_t)brow * K_DIM;      // fp32 A panel
    const bf16* Brow = Wb + (size_t)bcol * K_DIM;

    // per-lane LDS read offsets (bf16 units); swizzle term (row>>1)&3 == (r>>1)&3
    const int gswr = (r >> 1) & 3;
    const int aoff = (wr * 128 + r) * 32 + (q ^ gswr) * 8;
    const int boff = (wc * 64 + r) * 32 + (q ^ gswr) * 8;

    f32x4 acc[8][4];
#pragma unroll
    for (int m = 0; m < 8; ++m)
#pragma unroll
        for (int n = 0; n < 4; ++n) acc[m][n] = 0.0f;

    float4 va[4];  // in-flight fp32 A half-tile (statically indexed)

    // issue: 4 perfectly-coalesced dwordx4 (rows f>>3, float4 f&7)
#define A_ISSUE(kb) do {                                                          \
        _Pragma("unroll") for (int j = 0; j < 4; ++j) {                           \
            int f = j * 512 + tid;                                                \
            va[j] = *(const float4*)(Arowf + (size_t)(f >> 3) * K_DIM + (kb) + (f & 7) * 4); \
        }                                                                         \
    } while (0)

    // commit: cvt + ds_write_b64 at the READ-side swizzled position
    // (granule kg = k4>>1 stored at kg ^ ((row>>1)&3); matches aoff exactly)
#define A_COMMIT(slot) do {                                                       \
        _Pragma("unroll") for (int j = 0; j < 4; ++j) {                           \
            int f = j * 512 + tid;                                                \
            int row = f >> 3, k4 = f & 7;                                         \
            bf16x4 h;                                                             \
            h[0] = (bf16)va[j].x; h[1] = (bf16)va[j].y;                           \
            h[2] = (bf16)va[j].z; h[3] = (bf16)va[j].w;                           \
            int sw16 = (k4 >> 1) ^ ((row >> 1) & 3);                              \
            *(bf16x4*)((slot) + row * 32 + sw16 * 8 + (k4 & 1) * 4) = h;          \
        }                                                                         \
        asm volatile("" ::: "memory");  /* don't sink writes past barriers */     \
    } while (0)

    bf16x8 af[4], bfr[4];

#define READ_A(P, H, MH) {                                                        \
        _Pragma("unroll") for (int m = 0; m < 4; ++m)                             \
            af[m] = *(const bf16x8*)(ASL(P, H) + aoff + ((MH) * 4 + m) * 512);    \
    }
#define READ_B(P, H) {                                                            \
        _Pragma("unroll") for (int n = 0; n < 4; ++n)                             \
            bfr[n] = *(const bf16x8*)(BSL(P, H) + boff + n * 512);                \
    }

#define MFMA_PH(MH) do {                                                          \
        __builtin_amdgcn_s_barrier();                                             \
        __builtin_amdgcn_s_setprio(1);                                            \
        _Pragma("unroll") for (int m = 0; m < 4; ++m)                             \
            _Pragma("unroll") for (int n = 0; n < 4; ++n)                         \
                acc[(MH) * 4 + m][n] = __builtin_amdgcn_mfma_f32_16x16x32_bf16(   \
                    af[m], bfr[n], acc[(MH) * 4 + m][n], 0, 0, 0);                \
        __builtin_amdgcn_s_setprio(0);                                            \
        __builtin_amdgcn_s_barrier();                                             \
    } while (0)

    // ---- prologue: B halves t0h0,t0h1,t1h0 via gload_lds; A t0h0,t0h1
    // committed inline (one-time stall); A t1h0 left in va for P0's commit.
    stage_half(Brow, 0,  BSL(0, 0), tid);
    stage_half(Brow, 32, BSL(0, 1), tid);
    stage_half(Brow, 64, BSL(1, 0), tid);
    A_ISSUE(0);
    A_COMMIT(ASL(0, 0));   // va-wait also drains the 3 B stages (older)
    A_ISSUE(32);
    A_COMMIT(ASL(0, 1));
    A_ISSUE(64);           // t1h0 stays in flight
    __syncthreads();

    // ---- main loop: 16 iterations x 2 K-tiles (K=2048, BK=64) ----
    for (int i = 0; i < 16; ++i) {
        const int tb = 2 * i + 1;
        const int t2 = (2 * i + 2) & 31, t3 = (2 * i + 3) & 31;  // wrap: staged, never read
        // P0: commit A(1,0) [va from P6/prologue]; consume tile 2i kh0 (mh0);
        //     issue A+B (2i+1)h1
        A_COMMIT(ASL(1, 0));
        READ_A(0, 0, 0); READ_B(0, 0);
        A_ISSUE(tb * 64 + 32);
        stage_half(Brow, tb * 64 + 32, BSL(1, 1), tid);
        MFMA_PH(0);
        // P1
        READ_A(0, 0, 1);
        MFMA_PH(1);
        // P2: commit A(1,1); consume tile 2i kh1; issue A+B (2i+2)h0
        A_COMMIT(ASL(1, 1));
        READ_A(0, 1, 0); READ_B(0, 1);
        A_ISSUE(t2 * 64);
        stage_half(Brow, t2 * 64, BSL(0, 0), tid);
        MFMA_PH(0);
        // P3
        READ_A(0, 1, 1);
        MFMA_PH(1);
        // P4: commit A(0,0); consume tile 2i+1 kh0; issue A+B (2i+2)h1
        A_COMMIT(ASL(0, 0));
        READ_A(1, 0, 0); READ_B(1, 0);
        A_ISSUE(t2 * 64 + 32);
        stage_half(Brow, t2 * 64 + 32, BSL(0, 1), tid);
        MFMA_PH(0);
        // P5
        READ_A(1, 0, 1);
        MFMA_PH(1);
        // P6: commit A(0,1); consume tile 2i+1 kh1; issue A+B (2i+3)h0
        A_COMMIT(ASL(0, 1));
        READ_A(1, 1, 0); READ_B(1, 1);
        A_ISSUE(t3 * 64);
        stage_half(Brow, t3 * 64, BSL(1, 0), tid);
        MFMA_PH(0);
        // P7
        READ_A(1, 1, 1);
        MFMA_PH(1);
    }

    // ---- fused epilogue: GroupNorm (group == wave's 64-col span) + row min ----
    float gw[4], gb[4];
#pragma unroll
    for (int n = 0; n < 4; ++n) {
        int col = bcol + wc * 64 + n * 16 + r;
        gw[n] = gnw[col];
        gb[n] = gnb[col];
    }
#pragma unroll
    for (int m = 0; m < 8; ++m) {
#pragma unroll
        for (int j = 0; j < 4; ++j) {
            float s = 0.f, ss = 0.f;
#pragma unroll
            for (int n = 0; n < 4; ++n) {
                float v = acc[m][n][j];
                s += v; ss += v * v;
            }
#pragma unroll
            for (int d = 1; d < 16; d <<= 1) {
                s += __shfl_xor(s, d);
                ss += __shfl_xor(ss, d);
            }
            float mean = s * (1.f / 64.f);
            float var = ss * (1.f / 64.f) - mean * mean;
            float rstd = rsqrtf(var + EPSV);
            float mn = 3.4e38f;
#pragma unroll
            for (int n = 0; n < 4; ++n) {
                float y = (acc[m][n][j] - mean) * rstd * gw[n] + gb[n];
                mn = fminf(mn, y);
            }
#pragma unroll
            for (int d = 1; d < 16; d <<= 1) mn = fminf(mn, __shfl_xor(mn, d));
            if (r == 0)
                atomicMin(&rowmin[brow + wr * 128 + m * 16 + q * 4 + j], fenc(mn));
        }
    }
}

// out[m][n] = dec(rowmin[m]) + bias[n]
__global__ void bcast_kernel(const unsigned* __restrict__ rowmin,
                             const float* __restrict__ bias,
                             float* __restrict__ out) {
    const long total4 = (long)M_DIM * N_DIM / 4;
    long i = (long)blockIdx.x * blockDim.x + threadIdx.x;
    long stride = (long)gridDim.x * blockDim.x;
    for (; i < total4; i += stride) {
        int mrow = (int)(i >> 8);  // N/4 = 256 float4 per row
        int n4 = (int)(i & 255);
        float rm = fdec(rowmin[mrow]);
        float4 b = ((const float4*)bias)[n4];
        float4 o;
        o.x = rm + b.x; o.y = rm + b.y; o.z = rm + b.z; o.w = rm + b.w;
        ((float4*)out)[i] = o;
    }
}

extern "C" void kernel_launch(void* const* d_in, const int* in_sizes, int n_in,
                              void* d_out, int out_size, void* d_ws, size_t ws_size,
                              hipStream_t stream) {
    const float* x = (const float*)d_in[0];
    const float* w = (const float*)d_in[1];
    const float* gnw = (const float*)d_in[2];
    const float* gnb = (const float*)d_in[3];
    const float* bias = (const float*)d_in[4];

    unsigned char* ws = (unsigned char*)d_ws;
    unsigned* rowmin = (unsigned*)ws;                          // 256 KB
    bf16* wb = (bf16*)(ws + (size_t)M_DIM * 4);                // 4 MB

    hipFuncSetAttribute((const void*)gemm_fused,
                        hipFuncAttributeMaxDynamicSharedMemorySize, 131072);

    hipMemsetAsync(rowmin, 0xFF, (size_t)M_DIM * 4, stream);   // +inf in encoding
    cvt_kernel<<<512, 256, 0, stream>>>(w, wb, (long)N_DIM * K_DIM / 4);

    gemm_fused<<<dim3(1024), 512, 131072, stream>>>(x, wb, gnw, gnb, rowmin);

    bcast_kernel<<<2048, 256, 0, stream>>>(rowmin, bias, (float*)d_out);
}

// Round 6
// 523.343 us; speedup vs baseline: 1.0548x; 1.0548x over previous
//
#include <hip/hip_runtime.h>

#define M_DIM 65536
#define K_DIM 2048
#define N_DIM 1024
#define EPSV 1e-5f

typedef __bf16 bf16;
typedef bf16 bf16x8 __attribute__((ext_vector_type(8)));
typedef bf16 bf16x4 __attribute__((ext_vector_type(4)));
typedef float f32x4 __attribute__((ext_vector_type(4)));

// monotone float <-> uint encoding for atomicMin on float
__device__ inline unsigned fenc(float f) {
    unsigned u = __float_as_uint(f);
    return (u & 0x80000000u) ? ~u : (u | 0x80000000u);
}
__device__ inline float fdec(unsigned e) {
    unsigned u = (e & 0x80000000u) ? (e & 0x7fffffffu) : ~e;
    return __uint_as_float(u);
}

__device__ __forceinline__ void gload_lds16(const bf16* g, bf16* l) {
    __builtin_amdgcn_global_load_lds(
        (const __attribute__((address_space(1))) unsigned int*)g,
        (__attribute__((address_space(3))) unsigned int*)l, 16, 0, 0);
}

// fp32 -> bf16 conversion, vectorized
__global__ void cvt_kernel(const float* __restrict__ in, bf16* __restrict__ out, long n4) {
    long i = (long)blockIdx.x * blockDim.x + threadIdx.x;
    long stride = (long)gridDim.x * blockDim.x;
    for (; i < n4; i += stride) {
        float4 v = ((const float4*)in)[i];
        bf16x4 h;
        h[0] = (bf16)v.x; h[1] = (bf16)v.y; h[2] = (bf16)v.z; h[3] = (bf16)v.w;
        ((bf16x4*)out)[i] = h;
    }
}

// Stage one [256 rows][32 k] bf16 half-tile (16 KB): 512 threads x 2
// global_load_lds(16B). LDS dest LINEAR; XOR swizzle (granule ^= (row>>1)&3)
// applied to the GLOBAL source (both-sides involution). Conflict-free (R2: 0).
__device__ __forceinline__ void stage_half(const bf16* __restrict__ g0, int kbase,
                                           bf16* slot, int tid) {
#pragma unroll
    for (int i = 0; i < 2; ++i) {
        int gidx = i * 512 + tid;           // 16B granule id, 1024 per half-tile
        int row = gidx >> 2;                // 4 granules (64B) per row
        int gsw = (gidx & 3) ^ ((row >> 1) & 3);
        gload_lds16(g0 + (size_t)row * K_DIM + kbase + gsw * 8,
                    slot + (size_t)(i * 512 + (tid & 448)) * 8);  // wave-uniform base
    }
}

// LDS slots: A[parity][khalf], B[parity][khalf], each [256][32] bf16 = 16KB.
#define ASL(P, H) (lds + ((P) * 2 + (H)) * 8192)
#define BSL(P, H) (lds + 32768 + ((P) * 2 + (H)) * 8192)

// 256x256 tile, BK=64 as two K-halves of 32; 8 waves (2Mx4N), per-wave 128x64
// (8x4 frags of 16x16x32). 8 phases / 2 K-tiles per iter. READ-AHEAD pipeline:
// each phase issues ds_reads for the NEXT phase's fragments into a double
// register buffer (af[2]/bfr[2]), so LDS service overlaps the current MFMA
// cluster. Counted vmcnt gates sit at the TAIL of P0/P2/P4/P6 (before the
// closing barrier), each covering the slot first-read two phases later; the
// waited loads are 4-6 phases old => near-free. Stage placement, source-side
// swizzle, and the fused GroupNorm+rowmin epilogue are R4-proven.
__global__ __launch_bounds__(512, 2)
void gemm_fused(const bf16* __restrict__ Xb, const bf16* __restrict__ Wb,
                const float* __restrict__ gnw, const float* __restrict__ gnb,
                unsigned* __restrict__ rowmin) {
    extern __shared__ __align__(16) bf16 lds[];  // 128 KiB dynamic

    const int tid = threadIdx.x;
    const int wave = tid >> 6, lane = tid & 63;
    const int wr = wave >> 2, wc = wave & 3;     // 2 x 4 wave grid
    const int q = lane >> 4, r = lane & 15;

    // T1: bijective XCD-chunked block swizzle (1024 blocks % 8 == 0)
    const int bid = blockIdx.x;
    const int swz = (bid & 7) * 128 + (bid >> 3);
    const int bx = swz & 3, by = swz >> 2;
    const int brow = by * 256, bcol = bx * 256;

    const bf16* Arow = Xb + (size_t)brow * K_DIM;
    const bf16* Brow = Wb + (size_t)bcol * K_DIM;

    // per-lane LDS read offsets (bf16 units); swizzle term (row>>1)&3 == (r>>1)&3
    const int gswr = (r >> 1) & 3;
    const int aoff = (wr * 128 + r) * 32 + (q ^ gswr) * 8;
    const int boff = (wc * 64 + r) * 32 + (q ^ gswr) * 8;

    f32x4 acc[8][4];
#pragma unroll
    for (int m = 0; m < 8; ++m)
#pragma unroll
        for (int n = 0; n < 4; ++n) acc[m][n] = 0.0f;

    bf16x8 af[2][4], bfr[2][4];  // double-buffered fragments (read-ahead)

#define READ_A(BUF, P, H, MH) {                                                       \
        _Pragma("unroll") for (int m = 0; m < 4; ++m)                                 \
            af[BUF][m] = *(const bf16x8*)(ASL(P, H) + aoff + ((MH) * 4 + m) * 512);   \
    }
#define READ_B(BUF, P, H) {                                                           \
        _Pragma("unroll") for (int n = 0; n < 4; ++n)                                 \
            bfr[BUF][n] = *(const bf16x8*)(BSL(P, H) + boff + n * 512);               \
    }

    // MFMA phase: open barrier / setprio-wrapped cluster / optional counted
    // vmcnt gate / close barrier. Compiler inserts the fine-grained lgkmcnt
    // for the fragment deps (no manual pins — R3/R4 lesson).
#define MFMA_PH(AB, BB, MH) do {                                                      \
        __builtin_amdgcn_s_barrier();                                                 \
        __builtin_amdgcn_s_setprio(1);                                                \
        _Pragma("unroll") for (int m = 0; m < 4; ++m)                                 \
            _Pragma("unroll") for (int n = 0; n < 4; ++n)                             \
                acc[(MH) * 4 + m][n] = __builtin_amdgcn_mfma_f32_16x16x32_bf16(       \
                    af[AB][m], bfr[BB][n], acc[(MH) * 4 + m][n], 0, 0, 0);            \
        __builtin_amdgcn_s_setprio(0);                                                \
        __builtin_amdgcn_s_barrier();                                                 \
    } while (0)

#define MFMA_PH_GATE(AB, BB, MH, VMC) do {                                            \
        __builtin_amdgcn_s_barrier();                                                 \
        __builtin_amdgcn_s_setprio(1);                                                \
        _Pragma("unroll") for (int m = 0; m < 4; ++m)                                 \
            _Pragma("unroll") for (int n = 0; n < 4; ++n)                             \
                acc[(MH) * 4 + m][n] = __builtin_amdgcn_mfma_f32_16x16x32_bf16(       \
                    af[AB][m], bfr[BB][n], acc[(MH) * 4 + m][n], 0, 0, 0);            \
        __builtin_amdgcn_s_setprio(0);                                                \
        asm volatile("s_waitcnt vmcnt(" #VMC ")" ::: "memory");                       \
        __builtin_amdgcn_s_barrier();                                                 \
    } while (0)

    // ---- prologue: stage t0h0(A,B), t0h1(A,B), t1h0(A,B) = 12 loads/thread;
    // gate (t0h0 = oldest 4) with vmcnt(8)+barrier; preload buf0 fragments.
    stage_half(Arow, 0,  ASL(0, 0), tid);
    stage_half(Brow, 0,  BSL(0, 0), tid);
    stage_half(Arow, 32, ASL(0, 1), tid);
    stage_half(Brow, 32, BSL(0, 1), tid);
    stage_half(Arow, 64, ASL(1, 0), tid);
    stage_half(Brow, 64, BSL(1, 0), tid);
    asm volatile("s_waitcnt vmcnt(8)" ::: "memory");
    __builtin_amdgcn_s_barrier();
    READ_A(0, 0, 0, 0);   // A(0,0) mh0 -> af[0]
    READ_B(0, 0, 0);      // B(0,0)     -> bfr[0]

    // ---- main loop: 16 iterations x 2 K-tiles (K=2048, BK=64) ----
    // Phase p: [reads for phase p+1] [stages per R4 placement] [MFMA on buf p]
    for (int i = 0; i < 16; ++i) {
        const int tb = 2 * i + 1;
        const int t2 = (2 * i + 2) & 31, t3 = (2 * i + 3) & 31;  // wrap: staged, never read
        // P0: pre-read A(0,0)mh1; stage (2i+1)h1; MFMA af[0],bfr[0] mh0; gate P4(i-1) loads
        READ_A(1, 0, 0, 1);
        stage_half(Arow, tb * 64 + 32, ASL(1, 1), tid);
        stage_half(Brow, tb * 64 + 32, BSL(1, 1), tid);
        MFMA_PH_GATE(0, 0, 0, 8);
        // P1: pre-read A(0,1)mh0 + B(0,1); MFMA af[1],bfr[0] mh1
        READ_A(0, 0, 1, 0);
        READ_B(1, 0, 1);
        MFMA_PH(1, 0, 1);
        // P2: pre-read A(0,1)mh1; stage A(2i+2)h0; MFMA af[0],bfr[1] mh0; gate P6/P7(i-1)
        READ_A(1, 0, 1, 1);
        stage_half(Arow, t2 * 64, ASL(0, 0), tid);
        MFMA_PH_GATE(0, 1, 0, 6);
        // P3: pre-read A(1,0)mh0 + B(1,0); stage B(2i+2)h0; MFMA af[1],bfr[1] mh1
        READ_A(0, 1, 0, 0);
        READ_B(0, 1, 0);
        stage_half(Brow, t2 * 64, BSL(0, 0), tid);
        MFMA_PH(1, 1, 1);
        // P4: pre-read A(1,0)mh1; stage (2i+2)h1; MFMA af[0],bfr[0] mh0; gate P0 loads
        READ_A(1, 1, 0, 1);
        stage_half(Arow, t2 * 64 + 32, ASL(0, 1), tid);
        stage_half(Brow, t2 * 64 + 32, BSL(0, 1), tid);
        MFMA_PH_GATE(0, 0, 0, 8);
        // P5: pre-read A(1,1)mh0 + B(1,1); MFMA af[1],bfr[0] mh1
        READ_A(0, 1, 1, 0);
        READ_B(1, 1, 1);
        MFMA_PH(1, 0, 1);
        // P6: pre-read A(1,1)mh1; stage A(2i+3)h0; MFMA af[0],bfr[1] mh0; gate P2/P3 loads
        READ_A(1, 1, 1, 1);
        stage_half(Arow, t3 * 64, ASL(1, 0), tid);
        MFMA_PH_GATE(0, 1, 0, 6);
        // P7: pre-read A(0,0)mh0 + B(0,0) [tile 2i+2]; stage B(2i+3)h0; MFMA af[1],bfr[1] mh1
        READ_A(0, 0, 0, 0);
        READ_B(0, 0, 0);
        stage_half(Brow, t3 * 64, BSL(1, 0), tid);
        MFMA_PH(1, 1, 1);
    }

    // ---- fused epilogue: GroupNorm (group == wave's 64-col span) + row min ----
    float gw[4], gb[4];
#pragma unroll
    for (int n = 0; n < 4; ++n) {
        int col = bcol + wc * 64 + n * 16 + r;
        gw[n] = gnw[col];
        gb[n] = gnb[col];
    }
#pragma unroll
    for (int m = 0; m < 8; ++m) {
#pragma unroll
        for (int j = 0; j < 4; ++j) {
            float s = 0.f, ss = 0.f;
#pragma unroll
            for (int n = 0; n < 4; ++n) {
                float v = acc[m][n][j];
                s += v; ss += v * v;
            }
#pragma unroll
            for (int d = 1; d < 16; d <<= 1) {
                s += __shfl_xor(s, d);
                ss += __shfl_xor(ss, d);
            }
            float mean = s * (1.f / 64.f);
            float var = ss * (1.f / 64.f) - mean * mean;
            float rstd = rsqrtf(var + EPSV);
            float mn = 3.4e38f;
#pragma unroll
            for (int n = 0; n < 4; ++n) {
                float y = (acc[m][n][j] - mean) * rstd * gw[n] + gb[n];
                mn = fminf(mn, y);
            }
#pragma unroll
            for (int d = 1; d < 16; d <<= 1) mn = fminf(mn, __shfl_xor(mn, d));
            if (r == 0)
                atomicMin(&rowmin[brow + wr * 128 + m * 16 + q * 4 + j], fenc(mn));
        }
    }
}

// out[m][n] = dec(rowmin[m]) + bias[n]
__global__ void bcast_kernel(const unsigned* __restrict__ rowmin,
                             const float* __restrict__ bias,
                             float* __restrict__ out) {
    const long total4 = (long)M_DIM * N_DIM / 4;
    long i = (long)blockIdx.x * blockDim.x + threadIdx.x;
    long stride = (long)gridDim.x * blockDim.x;
    for (; i < total4; i += stride) {
        int mrow = (int)(i >> 8);  // N/4 = 256 float4 per row
        int n4 = (int)(i & 255);
        float rm = fdec(rowmin[mrow]);
        float4 b = ((const float4*)bias)[n4];
        float4 o;
        o.x = rm + b.x; o.y = rm + b.y; o.z = rm + b.z; o.w = rm + b.w;
        ((float4*)out)[i] = o;
    }
}

extern "C" void kernel_launch(void* const* d_in, const int* in_sizes, int n_in,
                              void* d_out, int out_size, void* d_ws, size_t ws_size,
                              hipStream_t stream) {
    const float* x = (const float*)d_in[0];
    const float* w = (const float*)d_in[1];
    const float* gnw = (const float*)d_in[2];
    const float* gnb = (const float*)d_in[3];
    const float* bias = (const float*)d_in[4];

    unsigned char* ws = (unsigned char*)d_ws;
    unsigned* rowmin = (unsigned*)ws;                          // 256 KB
    bf16* wb = (bf16*)(ws + (size_t)M_DIM * 4);                // 4 MB
    bf16* xb = (bf16*)(ws + (size_t)M_DIM * 4 + (size_t)N_DIM * K_DIM * 2);  // 256 MB

    hipFuncSetAttribute((const void*)gemm_fused,
                        hipFuncAttributeMaxDynamicSharedMemorySize, 131072);

    hipMemsetAsync(rowmin, 0xFF, (size_t)M_DIM * 4, stream);   // +inf in encoding
    cvt_kernel<<<512, 256, 0, stream>>>(w, wb, (long)N_DIM * K_DIM / 4);
    cvt_kernel<<<4096, 256, 0, stream>>>(x, xb, (long)M_DIM * K_DIM / 4);

    gemm_fused<<<dim3(1024), 512, 131072, stream>>>(xb, wb, gnw, gnb, rowmin);

    bcast_kernel<<<2048, 256, 0, stream>>>(rowmin, bias, (float*)d_out);
}